// Round 1
// baseline (337.284 us; speedup 1.0000x reference)
//
#include <hip/hip_runtime.h>

// Problem dims (fixed by setup_inputs)
#define BB 16
#define CR 1024
#define HWD 784     // 28*28
#define CS 256
#define SSZ 25      // Ws == Hs
#define CI 512
#define CSPLIT 8    // c-chunks in energy kernel (each CR/CSPLIT = 128)
#define RSPLIT 8    // r-chunks in out kernel (each 128)

// Workspace layout (floats). Total = 4,007,824 floats ~= 16.1 MB.
#define OFF_POOLED 0         // [B][CS][S]      = 102400   (pooled[b][c'][s])
#define OFF_G      102400    // [CR][CS]        = 262144   (G[c][c'] = sum_i Wq[i,c]Wk[i,c'])
#define OFF_GB     364544    // [CR]            = 1024     (gb[c]   = sum_i Wq[i,c]bk[i])
#define OFF_H      365568    // [CS]            = 256      (h[c']   = sum_i Wk[i,c']bq[i])
#define OFF_V      365824    // [B][CR][S]      = 409600   (v[b][r][s])
#define OFF_M      775424    // [B][CR][S]      = 409600   (M[b][c][s])
#define OFF_E0     1185024   // [B][S]          = 400
#define OFF_EP     1185424   // [CSPLIT][B][S][HW] = 2508800
#define OFF_ATT    3694224   // [B][S][HW]      = 313600

// ---------------- K0: G = Wq^T @ Wk  (1024x256, K=512) ----------------
// grid 128 blocks x 256 thr; block handles 8 c-rows (uniform -> s_load of Wq),
// lane = c' (coalesced Wk loads).
__global__ void k_G(const float* __restrict__ Wq, const float* __restrict__ Wk,
                    float* __restrict__ G) {
    int cp = threadIdx.x;            // c'
    int c0 = blockIdx.x * 8;         // c tile
    float acc[8];
#pragma unroll
    for (int j = 0; j < 8; ++j) acc[j] = 0.f;
    for (int i = 0; i < CI; ++i) {
        float wk = Wk[i * CS + cp];                  // coalesced vector load
        const float* wq = Wq + i * CR + c0;          // uniform -> scalar loads
#pragma unroll
        for (int j = 0; j < 8; ++j) acc[j] = fmaf(wq[j], wk, acc[j]);
    }
#pragma unroll
    for (int j = 0; j < 8; ++j) G[(c0 + j) * CS + cp] = acc[j];
}

// ---------------- K0b: gb[c] = Wq^T bk ; h[c'] = Wk^T bq ----------------
__global__ void k_bias(const float* __restrict__ Wq, const float* __restrict__ Wk,
                       const float* __restrict__ bq, const float* __restrict__ bk,
                       float* __restrict__ gb, float* __restrict__ h) {
    if (blockIdx.x < 4) {
        int c = blockIdx.x * 256 + threadIdx.x;      // 0..1023
        float a = 0.f;
        for (int i = 0; i < CI; ++i) a = fmaf(Wq[i * CR + c], bk[i], a);
        gb[c] = a;
    } else {
        int cp = threadIdx.x;                        // 0..255
        float a = 0.f;
        for (int i = 0; i < CI; ++i) a = fmaf(Wk[i * CS + cp], bq[i], a);
        h[cp] = a;
    }
}

// ---------------- K1: pooled[b][c][s] = mean_w x_skel[b][c][s][w] ----------------
// t enumerates (b,c,s) with s fastest; input row is 25 contiguous floats.
__global__ void k_pool(const float* __restrict__ xs, float* __restrict__ pooled) {
    int t = blockIdx.x * 256 + threadIdx.x;          // 0..102399
    const float* p = xs + (size_t)t * SSZ;
    float a = 0.f;
#pragma unroll
    for (int w = 0; w < SSZ; ++w) a += p[w];
    pooled[t] = a * (1.0f / SSZ);
}

// ---------------- K2v: v[b][r][s] = Wv[r,:]·pooled[b,:,s] + bv[r] ----------------
// thread per (b,r). Wv row via per-lane float4; pooled via uniform scalar loads.
__global__ void k_v(const float* __restrict__ Wv, const float* __restrict__ bv,
                    const float* __restrict__ pooled, float* __restrict__ v) {
    int r = blockIdx.x * 256 + threadIdx.x;          // grid.x = 4
    int b = blockIdx.y;
    const float* pb = pooled + (size_t)b * CS * SSZ;
    const float4* w4 = (const float4*)(Wv + (size_t)r * CS);
    float acc[SSZ];
#pragma unroll
    for (int s = 0; s < SSZ; ++s) acc[s] = 0.f;
    for (int c4 = 0; c4 < CS / 4; ++c4) {
        float4 w = w4[c4];
        const float* p = pb + c4 * 4 * SSZ;          // uniform -> s_load
#pragma unroll
        for (int s = 0; s < SSZ; ++s)
            acc[s] = fmaf(w.x, p[s],
                     fmaf(w.y, p[SSZ + s],
                     fmaf(w.z, p[2 * SSZ + s],
                     fmaf(w.w, p[3 * SSZ + s], acc[s]))));
    }
    float bvr = bv[r];
    float* vr = v + ((size_t)b * CR + r) * SSZ;
#pragma unroll
    for (int s = 0; s < SSZ; ++s) vr[s] = acc[s] + bvr;
}

// ---------------- K3: M[b][c][s] = G[c,:]·pooled[b,:,s] + gb[c] ----------------
__global__ void k_M(const float* __restrict__ G, const float* __restrict__ gb,
                    const float* __restrict__ pooled, float* __restrict__ M) {
    int c = blockIdx.x * 256 + threadIdx.x;          // grid.x = 4
    int b = blockIdx.y;
    const float* pb = pooled + (size_t)b * CS * SSZ;
    const float4* g4 = (const float4*)(G + (size_t)c * CS);
    float acc[SSZ];
#pragma unroll
    for (int s = 0; s < SSZ; ++s) acc[s] = 0.f;
    for (int c4 = 0; c4 < CS / 4; ++c4) {
        float4 g = g4[c4];
        const float* p = pb + c4 * 4 * SSZ;
#pragma unroll
        for (int s = 0; s < SSZ; ++s)
            acc[s] = fmaf(g.x, p[s],
                     fmaf(g.y, p[SSZ + s],
                     fmaf(g.z, p[2 * SSZ + s],
                     fmaf(g.w, p[3 * SSZ + s], acc[s]))));
    }
    float g0 = gb[c];
    float* mr = M + ((size_t)b * CR + c) * SSZ;
#pragma unroll
    for (int s = 0; s < SSZ; ++s) mr[s] = acc[s] + g0;
}

// ---------------- K3b: e0[b][s] = h·pooled[b,:,s] + bq·bk ----------------
__global__ void k_e0(const float* __restrict__ h, const float* __restrict__ bq,
                     const float* __restrict__ bk, const float* __restrict__ pooled,
                     float* __restrict__ e0) {
    int t = blockIdx.x * 256 + threadIdx.x;
    if (t >= BB * SSZ) return;
    int b = t / SSZ, s = t % SSZ;
    float a = 0.f;
    for (int i = 0; i < CI; ++i) a = fmaf(bq[i], bk[i], a);   // uniform, hoisted
    const float* pb = pooled + (size_t)b * CS * SSZ + s;
    for (int cp = 0; cp < CS; ++cp) a = fmaf(h[cp], pb[cp * SSZ], a);
    e0[t] = a;
}

// ---------------- K4: partial energies Ep[ch][b][s][n] ----------------
// lane = n (coalesced x_rgb), c-chunk from blockIdx.z (uniform M rows -> s_load)
__global__ void k_energy(const float* __restrict__ xr, const float* __restrict__ M,
                         float* __restrict__ Ep) {
    int n = blockIdx.x * 64 + threadIdx.x;           // grid.x = 13
    int b = blockIdx.y;
    int ch = blockIdx.z;                             // 0..CSPLIT-1
    bool valid = n < HWD;
    int nc = valid ? n : HWD - 1;
    const float* xb = xr + (size_t)b * CR * HWD;
    const float* Mb = M + (size_t)b * CR * SSZ;
    float acc[SSZ];
#pragma unroll
    for (int s = 0; s < SSZ; ++s) acc[s] = 0.f;
    int cbeg = ch * (CR / CSPLIT);
    for (int c = cbeg; c < cbeg + CR / CSPLIT; ++c) {
        float x = xb[(size_t)c * HWD + nc];          // coalesced
        const float* m = Mb + (size_t)c * SSZ;       // uniform -> s_load
#pragma unroll
        for (int s = 0; s < SSZ; ++s) acc[s] = fmaf(x, m[s], acc[s]);
    }
    if (valid) {
        float* ep = Ep + ((size_t)(ch * BB + b) * SSZ) * HWD + n;
#pragma unroll
        for (int s = 0; s < SSZ; ++s) ep[(size_t)s * HWD] = acc[s];  // coalesced
    }
}

// ---------------- K4b: att[b][s][n] = softmax_s( sum_ch Ep + e0 ) ----------------
__global__ void k_softmax(const float* __restrict__ Ep, const float* __restrict__ e0,
                          float* __restrict__ att) {
    int n = blockIdx.x * 64 + threadIdx.x;           // grid.x = 13
    int b = blockIdx.y;
    if (n >= HWD) return;
    float e[SSZ];
#pragma unroll
    for (int s = 0; s < SSZ; ++s) e[s] = e0[b * SSZ + s];
    for (int ch = 0; ch < CSPLIT; ++ch) {
        const float* ep = Ep + ((size_t)(ch * BB + b) * SSZ) * HWD + n;
#pragma unroll
        for (int s = 0; s < SSZ; ++s) e[s] += ep[(size_t)s * HWD];
    }
    float m = e[0];
#pragma unroll
    for (int s = 1; s < SSZ; ++s) m = fmaxf(m, e[s]);
    float sum = 0.f;
#pragma unroll
    for (int s = 0; s < SSZ; ++s) { e[s] = __expf(e[s] - m); sum += e[s]; }
    float inv = 1.0f / sum;
    float* ao = att + ((size_t)b * SSZ) * HWD + n;
#pragma unroll
    for (int s = 0; s < SSZ; ++s) ao[(size_t)s * HWD] = e[s] * inv;
}

// ---------------- K5: out[b][r][n] = gamma * v[b][r,:]·att[b,:,n] + x_rgb ----------------
// lane = n, r-chunk from blockIdx.z; v rows uniform -> s_load.
__global__ void k_out(const float* __restrict__ xr, const float* __restrict__ v,
                      const float* __restrict__ att, const float* __restrict__ gamma,
                      float* __restrict__ out) {
    int n = blockIdx.x * 64 + threadIdx.x;           // grid.x = 13
    int b = blockIdx.y;
    int rz = blockIdx.z;                             // 0..RSPLIT-1
    bool valid = n < HWD;
    int nc = valid ? n : HWD - 1;
    float a[SSZ];
    const float* ab = att + (size_t)b * SSZ * HWD + nc;
#pragma unroll
    for (int s = 0; s < SSZ; ++s) a[s] = ab[(size_t)s * HWD];   // coalesced
    float g = gamma[0];
    int r0 = rz * (CR / RSPLIT);
    const float* xb = xr + (size_t)b * CR * HWD;
    float* ob = out + (size_t)b * CR * HWD;
    for (int r = r0; r < r0 + CR / RSPLIT; ++r) {
        const float* vr = v + ((size_t)b * CR + r) * SSZ;        // uniform -> s_load
        float d = 0.f;
#pragma unroll
        for (int s = 0; s < SSZ; ++s) d = fmaf(vr[s], a[s], d);
        if (valid)
            ob[(size_t)r * HWD + n] = fmaf(g, d, xb[(size_t)r * HWD + n]);
    }
}

extern "C" void kernel_launch(void* const* d_in, const int* in_sizes, int n_in,
                              void* d_out, int out_size, void* d_ws, size_t ws_size,
                              hipStream_t stream) {
    const float* x_rgb  = (const float*)d_in[0];
    const float* x_skel = (const float*)d_in[1];
    const float* Wq     = (const float*)d_in[2];
    const float* bq     = (const float*)d_in[3];
    const float* Wk     = (const float*)d_in[4];
    const float* bk     = (const float*)d_in[5];
    const float* Wv     = (const float*)d_in[6];
    const float* bv     = (const float*)d_in[7];
    const float* gamma  = (const float*)d_in[8];
    float* out = (float*)d_out;

    float* ws     = (float*)d_ws;
    float* pooled = ws + OFF_POOLED;
    float* G      = ws + OFF_G;
    float* gb     = ws + OFF_GB;
    float* h      = ws + OFF_H;
    float* v      = ws + OFF_V;
    float* M      = ws + OFF_M;
    float* e0     = ws + OFF_E0;
    float* Ep     = ws + OFF_EP;
    float* att    = ws + OFF_ATT;

    k_G      <<<dim3(128),        256, 0, stream>>>(Wq, Wk, G);
    k_bias   <<<dim3(5),          256, 0, stream>>>(Wq, Wk, bq, bk, gb, h);
    k_pool   <<<dim3(400),        256, 0, stream>>>(x_skel, pooled);
    k_v      <<<dim3(4, 16),      256, 0, stream>>>(Wv, bv, pooled, v);
    k_M      <<<dim3(4, 16),      256, 0, stream>>>(G, gb, pooled, M);
    k_e0     <<<dim3(2),          256, 0, stream>>>(h, bq, bk, pooled, e0);
    k_energy <<<dim3(13, 16, CSPLIT), 64, 0, stream>>>(x_rgb, M, Ep);
    k_softmax<<<dim3(13, 16),     64, 0, stream>>>(Ep, e0, att);
    k_out    <<<dim3(13, 16, RSPLIT), 64, 0, stream>>>(x_rgb, v, att, gamma, out);
}

// Round 2
// 282.144 us; speedup vs baseline: 1.1954x; 1.1954x over previous
//
#include <hip/hip_runtime.h>

// Problem dims (fixed by setup_inputs)
#define BB 16
#define CR 1024
#define HWD 784     // 28*28
#define HW2 392     // HWD/2 (float2 units)
#define CS 256
#define SSZ 25
#define SP 28       // padded row length for M/v (112B = 7 x float4)
#define CI 512
#define CSPLIT 8    // c-chunks in energy (each 128)
#define CCHUNK 128
#define RSPLIT 16   // r-chunks in out (each 64)
#define RCHUNK 64

// Workspace layout (floats). Total = 3,843,984 floats ~= 15.4 MB.
// G (262144) aliases the head of Ep: k_proj (last G reader) completes before
// k_energy (first Ep writer) by stream ordering.
#define OFF_POOLED 0          // [B][CS][S]        = 102400
#define OFF_GB     102400     // [CR]              = 1024
#define OFF_H      103424     // [CS]              = 256
#define OFF_VP     103680     // [B][CR][SP]       = 458752
#define OFF_MP     562432     // [B][CR][SP]       = 458752
#define OFF_E0     1021184    // [B][S]            = 400
#define OFF_ATT    1021584    // [B][S][HW]        = 313600
#define OFF_EPG    1335184    // Ep [CSPLIT][B][S][HW] = 2508800 (G aliased at start)

// ---------------- K0: G = Wq^T @ Wk (1024x256, K=512) ----------------
// 256 blocks x 256 thr; lane = c' (coalesced Wk); 4 c-rows via uniform float4 s_load.
__global__ __launch_bounds__(256) void k_G(const float* __restrict__ Wq,
                                           const float* __restrict__ Wk,
                                           float* __restrict__ G) {
    int cp = threadIdx.x;
    int c0 = blockIdx.x * 4;
    float a0 = 0.f, a1 = 0.f, a2 = 0.f, a3 = 0.f;
#pragma unroll 4
    for (int i = 0; i < CI; ++i) {
        float wk = Wk[(size_t)i * CS + cp];
        float4 wq = *(const float4*)(Wq + (size_t)i * CR + c0);
        a0 = fmaf(wq.x, wk, a0);
        a1 = fmaf(wq.y, wk, a1);
        a2 = fmaf(wq.z, wk, a2);
        a3 = fmaf(wq.w, wk, a3);
    }
    G[(size_t)(c0 + 0) * CS + cp] = a0;
    G[(size_t)(c0 + 1) * CS + cp] = a1;
    G[(size_t)(c0 + 2) * CS + cp] = a2;
    G[(size_t)(c0 + 3) * CS + cp] = a3;
}

// ---------------- K0b: gb[c] = Wq^T bk ; h[c'] = Wk^T bq ----------------
__global__ __launch_bounds__(256) void k_bias(const float* __restrict__ Wq,
                                              const float* __restrict__ Wk,
                                              const float* __restrict__ bq,
                                              const float* __restrict__ bk,
                                              float* __restrict__ gb,
                                              float* __restrict__ h) {
    if (blockIdx.x < 4) {
        int c = blockIdx.x * 256 + threadIdx.x;
        float a = 0.f;
        for (int i = 0; i < CI; ++i) a = fmaf(Wq[(size_t)i * CR + c], bk[i], a);
        gb[c] = a;
    } else {
        int cp = threadIdx.x;
        float a = 0.f;
        for (int i = 0; i < CI; ++i) a = fmaf(Wk[(size_t)i * CS + cp], bq[i], a);
        h[cp] = a;
    }
}

// ---------------- K1: pooled = mean over width (rows of 25 floats) ----------------
// Wave-cooperative: each wave stages 16 rows (100 float4, contiguous) to LDS,
// then 16 lanes reduce one row each. Avoids 25 strided scalar loads/thread.
__global__ __launch_bounds__(256) void k_pool(const float* __restrict__ xs,
                                              float* __restrict__ pooled) {
    __shared__ float buf[4][400];
    int wave = threadIdx.x >> 6, lane = threadIdx.x & 63;
    int r0 = blockIdx.x * 64 + wave * 16;          // 16 rows per wave
    const float4* src = (const float4*)(xs + (size_t)r0 * SSZ);   // 100 float4, 16B-aligned
    float4* b4 = (float4*)buf[wave];
    b4[lane] = src[lane];
    if (lane < 36) b4[64 + lane] = src[64 + lane];
    __syncthreads();
    if (lane < 16) {
        const float* row = buf[wave] + lane * SSZ;
        float s = 0.f;
#pragma unroll
        for (int w = 0; w < SSZ; ++w) s += row[w];
        pooled[r0 + lane] = s * (1.0f / SSZ);
    }
}

// ---------------- K2: fused M and v projections (padded rows, zeroed pads) ----------
// M[b][c][s] = G[c,:]·pooled[b,:,s] + gb[c];  v[b][r][s] = Wv[r,:]·pooled[b,:,s] + bv[r]
template <int NS>
__device__ __forceinline__ void proj_body(const float* __restrict__ wrow,
                                          const float* __restrict__ pb, int s0,
                                          float bias, float* __restrict__ dst,
                                          bool zpad) {
    float acc[NS];
#pragma unroll
    for (int i = 0; i < NS; ++i) acc[i] = 0.f;
    const float4* w4 = (const float4*)wrow;
#pragma unroll 2
    for (int c4 = 0; c4 < CS / 4; ++c4) {
        float4 w = w4[c4];
        const float* p = pb + c4 * 4 * SSZ + s0;   // uniform -> s_load
#pragma unroll
        for (int i = 0; i < NS; ++i)
            acc[i] = fmaf(w.x, p[i],
                     fmaf(w.y, p[SSZ + i],
                     fmaf(w.z, p[2 * SSZ + i],
                     fmaf(w.w, p[3 * SSZ + i], acc[i]))));
    }
#pragma unroll
    for (int i = 0; i < NS; ++i) dst[s0 + i] = acc[i] + bias;
    if (zpad) { dst[25] = 0.f; dst[26] = 0.f; dst[27] = 0.f; }
}

__global__ __launch_bounds__(256) void k_proj(const float* __restrict__ G,
                                              const float* __restrict__ Wv,
                                              const float* __restrict__ gb,
                                              const float* __restrict__ bv,
                                              const float* __restrict__ pooled,
                                              float* __restrict__ Mp,
                                              float* __restrict__ vp) {
    int q = blockIdx.x, b = blockIdx.y;
    int which = q & 1, cblk = (q >> 1) & 3, sh = q >> 3;
    int row = cblk * 256 + threadIdx.x;
    const float* pb = pooled + (size_t)b * CS * SSZ;
    const float* wrow = (which ? Wv : G) + (size_t)row * CS;
    float bias = which ? bv[row] : gb[row];
    float* dst = (which ? vp : Mp) + ((size_t)b * CR + row) * SP;
    if (sh == 0) proj_body<13>(wrow, pb, 0, bias, dst, false);
    else         proj_body<12>(wrow, pb, 13, bias, dst, true);
}

// ---------------- K3b: e0[b][s] = h·pooled[b,:,s] + bq·bk ----------------
__global__ __launch_bounds__(256) void k_e0(const float* __restrict__ h,
                                            const float* __restrict__ bq,
                                            const float* __restrict__ bk,
                                            const float* __restrict__ pooled,
                                            float* __restrict__ e0) {
    int t = blockIdx.x * 256 + threadIdx.x;
    if (t >= BB * SSZ) return;
    int b = t / SSZ, s = t % SSZ;
    float a = 0.f;
    for (int i = 0; i < CI; ++i) a = fmaf(bq[i], bk[i], a);
    const float* pb = pooled + (size_t)b * CS * SSZ + s;
    for (int cp = 0; cp < CS; ++cp) a = fmaf(h[cp], pb[cp * SSZ], a);
    e0[t] = a;
}

// ---------------- K4: partial energies Ep[ch][b][s][n], float2 lanes ----------------
// M chunk (128 rows x 28) staged in LDS; inner loop: 1 float2 global + 7 ds_read_b128
// (same-address broadcast, conflict-free) + 56 FMA.
__global__ __launch_bounds__(64) void k_energy(const float* __restrict__ xr,
                                               const float* __restrict__ Mp,
                                               float* __restrict__ Ep) {
    __shared__ float ldsM[CCHUNK * SP];            // 14336 B
    int lane = threadIdx.x;
    int b = blockIdx.y, ch = blockIdx.z;
    int cbeg = ch * CCHUNK;
    // stage M chunk: 896 float4, 14 per lane
    {
        const float4* src = (const float4*)(Mp + ((size_t)b * CR + cbeg) * SP);
        float4* dst = (float4*)ldsM;
#pragma unroll
        for (int j = 0; j < 14; ++j) dst[lane + 64 * j] = src[lane + 64 * j];
    }
    __syncthreads();

    int n2 = blockIdx.x * 64 + lane;               // float2 col index
    bool valid = n2 < HW2;
    int n2c = valid ? n2 : 0;
    const float2* x2 = (const float2*)(xr + (size_t)b * CR * HWD);

    float acc0[SP], acc1[SP];
#pragma unroll
    for (int s = 0; s < SP; ++s) { acc0[s] = 0.f; acc1[s] = 0.f; }

#pragma unroll 2
    for (int c = 0; c < CCHUNK; ++c) {
        float2 xv = x2[(size_t)(cbeg + c) * HW2 + n2c];
        const float4* mr = (const float4*)&ldsM[c * SP];
#pragma unroll
        for (int j = 0; j < 7; ++j) {
            float4 m = mr[j];
            acc0[4 * j + 0] = fmaf(xv.x, m.x, acc0[4 * j + 0]);
            acc0[4 * j + 1] = fmaf(xv.x, m.y, acc0[4 * j + 1]);
            acc0[4 * j + 2] = fmaf(xv.x, m.z, acc0[4 * j + 2]);
            acc0[4 * j + 3] = fmaf(xv.x, m.w, acc0[4 * j + 3]);
            acc1[4 * j + 0] = fmaf(xv.y, m.x, acc1[4 * j + 0]);
            acc1[4 * j + 1] = fmaf(xv.y, m.y, acc1[4 * j + 1]);
            acc1[4 * j + 2] = fmaf(xv.y, m.z, acc1[4 * j + 2]);
            acc1[4 * j + 3] = fmaf(xv.y, m.w, acc1[4 * j + 3]);
        }
    }
    if (valid) {
        float2* ep = (float2*)Ep + ((size_t)(ch * BB + b) * SSZ) * HW2 + n2;
#pragma unroll
        for (int s = 0; s < SSZ; ++s) ep[(size_t)s * HW2] = make_float2(acc0[s], acc1[s]);
    }
}

// ---------------- K4b: att = softmax_s(sum_ch Ep + e0), float2 lanes ----------------
__global__ __launch_bounds__(64) void k_softmax(const float* __restrict__ Ep,
                                                const float* __restrict__ e0,
                                                float* __restrict__ att) {
    int lane = threadIdx.x;
    int n2 = blockIdx.x * 64 + lane;
    int b = blockIdx.y;
    if (n2 >= HW2) return;
    float ex[SSZ], ey[SSZ];
#pragma unroll
    for (int s = 0; s < SSZ; ++s) { float v = e0[b * SSZ + s]; ex[s] = v; ey[s] = v; }
    const float2* ep2 = (const float2*)Ep;
    for (int ch = 0; ch < CSPLIT; ++ch) {
        const float2* ep = ep2 + ((size_t)(ch * BB + b) * SSZ) * HW2 + n2;
#pragma unroll
        for (int s = 0; s < SSZ; ++s) {
            float2 v = ep[(size_t)s * HW2];
            ex[s] += v.x; ey[s] += v.y;
        }
    }
    float mx = ex[0], my = ey[0];
#pragma unroll
    for (int s = 1; s < SSZ; ++s) { mx = fmaxf(mx, ex[s]); my = fmaxf(my, ey[s]); }
    float sx = 0.f, sy = 0.f;
#pragma unroll
    for (int s = 0; s < SSZ; ++s) {
        ex[s] = __expf(ex[s] - mx); sx += ex[s];
        ey[s] = __expf(ey[s] - my); sy += ey[s];
    }
    float ix = 1.0f / sx, iy = 1.0f / sy;
    float2* ao = (float2*)att + ((size_t)b * SSZ) * HW2 + n2;
#pragma unroll
    for (int s = 0; s < SSZ; ++s) ao[(size_t)s * HW2] = make_float2(ex[s] * ix, ey[s] * iy);
}

// ---------------- K5: out = gamma * (v·att) + x_rgb, float2 lanes ----------------
// v chunk (64 rows x 28) staged in LDS; att held in registers.
__global__ __launch_bounds__(64) void k_out(const float* __restrict__ xr,
                                            const float* __restrict__ vp,
                                            const float* __restrict__ att,
                                            const float* __restrict__ gamma,
                                            float* __restrict__ out) {
    __shared__ float ldsv[RCHUNK * SP];            // 7168 B
    int lane = threadIdx.x;
    int b = blockIdx.y, rz = blockIdx.z;
    int r0 = rz * RCHUNK;
    {
        const float4* src = (const float4*)(vp + ((size_t)b * CR + r0) * SP);
        float4* dst = (float4*)ldsv;
#pragma unroll
        for (int j = 0; j < 7; ++j) dst[lane + 64 * j] = src[lane + 64 * j];
    }
    __syncthreads();

    int n2 = blockIdx.x * 64 + lane;
    bool valid = n2 < HW2;
    int n2c = valid ? n2 : 0;

    float a0[SP], a1[SP];
    const float2* at2 = (const float2*)att + ((size_t)b * SSZ) * HW2 + n2c;
#pragma unroll
    for (int s = 0; s < SSZ; ++s) {
        float2 av = at2[(size_t)s * HW2];
        a0[s] = av.x; a1[s] = av.y;
    }
#pragma unroll
    for (int s = SSZ; s < SP; ++s) { a0[s] = 0.f; a1[s] = 0.f; }

    float g = gamma[0];
    const float2* x2 = (const float2*)(xr + (size_t)b * CR * HWD);
    float2* o2 = (float2*)(out + (size_t)b * CR * HWD);

#pragma unroll 2
    for (int r = 0; r < RCHUNK; ++r) {
        float d0 = 0.f, d1 = 0.f;
        const float4* vr = (const float4*)&ldsv[r * SP];
#pragma unroll
        for (int j = 0; j < 7; ++j) {
            float4 v = vr[j];
            d0 = fmaf(v.x, a0[4 * j + 0], d0);
            d0 = fmaf(v.y, a0[4 * j + 1], d0);
            d0 = fmaf(v.z, a0[4 * j + 2], d0);
            d0 = fmaf(v.w, a0[4 * j + 3], d0);
            d1 = fmaf(v.x, a1[4 * j + 0], d1);
            d1 = fmaf(v.y, a1[4 * j + 1], d1);
            d1 = fmaf(v.z, a1[4 * j + 2], d1);
            d1 = fmaf(v.w, a1[4 * j + 3], d1);
        }
        float2 xv = x2[(size_t)(r0 + r) * HW2 + n2c];
        if (valid)
            o2[(size_t)(r0 + r) * HW2 + n2] = make_float2(fmaf(g, d0, xv.x), fmaf(g, d1, xv.y));
    }
}

extern "C" void kernel_launch(void* const* d_in, const int* in_sizes, int n_in,
                              void* d_out, int out_size, void* d_ws, size_t ws_size,
                              hipStream_t stream) {
    const float* x_rgb  = (const float*)d_in[0];
    const float* x_skel = (const float*)d_in[1];
    const float* Wq     = (const float*)d_in[2];
    const float* bq     = (const float*)d_in[3];
    const float* Wk     = (const float*)d_in[4];
    const float* bk     = (const float*)d_in[5];
    const float* Wv     = (const float*)d_in[6];
    const float* bv     = (const float*)d_in[7];
    const float* gamma  = (const float*)d_in[8];
    float* out = (float*)d_out;

    float* ws     = (float*)d_ws;
    float* pooled = ws + OFF_POOLED;
    float* gb     = ws + OFF_GB;
    float* h      = ws + OFF_H;
    float* vp     = ws + OFF_VP;
    float* Mp     = ws + OFF_MP;
    float* e0     = ws + OFF_E0;
    float* att    = ws + OFF_ATT;
    float* Ep     = ws + OFF_EPG;
    float* G      = ws + OFF_EPG;   // alias: G dead before Ep written

    k_G      <<<dim3(256),            256, 0, stream>>>(Wq, Wk, G);
    k_bias   <<<dim3(5),              256, 0, stream>>>(Wq, Wk, bq, bk, gb, h);
    k_pool   <<<dim3(1600),           256, 0, stream>>>(x_skel, pooled);
    k_proj   <<<dim3(16, 16),         256, 0, stream>>>(G, Wv, gb, bv, pooled, Mp, vp);
    k_e0     <<<dim3(2),              256, 0, stream>>>(h, bq, bk, pooled, e0);
    k_energy <<<dim3(7, 16, CSPLIT),   64, 0, stream>>>(x_rgb, Mp, Ep);
    k_softmax<<<dim3(7, 16),           64, 0, stream>>>(Ep, e0, att);
    k_out    <<<dim3(7, 16, RSPLIT),   64, 0, stream>>>(x_rgb, vp, att, gamma, out);
}